// Round 3
// baseline (506.259 us; speedup 1.0000x reference)
//
#include <hip/hip_runtime.h>
#include <hip/hip_bf16.h>
#include <hip/hip_fp8.h>
#include <stdint.h>

#define B_      8
#define GRID_   24
#define C_      768
#define NPATCH  (B_*GRID_*GRID_)   // 4608
#define PRE     1024
#define TGT     1024
#define NMEM    20000
#define NMEM_PAD 20096             // 157 * 128
#define IMG_    384
#define SEQ     577                // GRID*GRID + 1

typedef int   intx4  __attribute__((ext_vector_type(4)));
typedef int   intx8  __attribute__((ext_vector_type(8)));
typedef float floatx4 __attribute__((ext_vector_type(4)));

// ---------------------------------------------------------------------------
// Kernel A: per-patch pooled embedding -> fp8 e4m3 + ||e_quantized||^2.
// Pooling math identical to round 2 (verified). Thread 0 also seeds psbits.
// ---------------------------------------------------------------------------
__global__ __launch_bounds__(256) void emb_kernel(
    const float* __restrict__ f6, const float* __restrict__ f8,
    const float* __restrict__ f10,
    uint8_t* __restrict__ emb, float* __restrict__ enorm,
    int* __restrict__ psbits)
{
    __shared__ float pooled[3*PRE];   // 12 KB
    __shared__ float red[4];

    const int n   = blockIdx.x;
    const int b   = n / (GRID_*GRID_);
    const int yx  = n - b*(GRID_*GRID_);
    const int y   = yx / GRID_;
    const int x   = yx - y*GRID_;
    const int t   = threadIdx.x;

    if (t == 0) psbits[n] = 0x7f7f7f7f;   // +INF-ish float bits for atomicMin

    const float* fl[3] = {f6, f8, f10};

#pragma unroll
    for (int l = 0; l < 3; ++l) {
        const float* f = fl[l];
        float A0 = 0.f, B0 = 0.f, C1 = 0.f, D1 = 0.f, E2 = 0.f, F2 = 0.f;
#pragma unroll
        for (int k = 0; k < 9; ++k) {
            const int kh = k / 3, kw = k - kh*3;
            const int ny = y + kh - 1, nx = x + kw - 1;
            const bool v = (ny >= 0 && ny < GRID_ && nx >= 0 && nx < GRID_);
            const int off = v ? (b*SEQ + 1 + ny*GRID_ + nx) : (b*SEQ);
            const float* p = f + (size_t)off*C_ + 3*t;
            float a = p[0], bq = p[1], c = p[2];
            if (!v) { a = 0.f; bq = 0.f; c = 0.f; }
            if (k <= 6) A0 += a;
            if (k >= 6) B0 += a;
            if (k <= 4) C1 += bq;
            if (k >= 4) D1 += bq;
            if (k <= 2) E2 += c;
            if (k >= 2) F2 += c;
        }
        float4 pv;
        pv.x = A0 * (1.f/7.f);
        pv.y = (B0 + C1) * (1.f/8.f);
        pv.z = (D1 + E2) * (1.f/8.f);
        pv.w = F2 * (1.f/7.f);
        *(float4*)(pooled + l*PRE + 4*t) = pv;
    }
    __syncthreads();

    // Aggregator + fp8 quantization (norm from the QUANTIZED values so that
    // d2 = ||e_q||^2 + ||m_q||^2 - 2 e_q.m_q == ||e_q - m_q||^2 exactly)
    float psq = 0.f;
    unsigned ob = 0;
#pragma unroll
    for (int r = 0; r < 4; ++r) {
        const int j = 4*t + r;
        float vv = (pooled[3*j] + pooled[3*j+1] + pooled[3*j+2]) * (1.f/3.f);
        __hip_fp8_e4m3 q(vv);
        ob |= ((unsigned)q.__x) << (8*r);
        float dq = (float)q;
        psq += dq*dq;
    }
    *(unsigned*)(emb + (size_t)n*TGT + 4*t) = ob;

    for (int off = 32; off > 0; off >>= 1) psq += __shfl_down(psq, off, 64);
    if ((t & 63) == 0) red[t >> 6] = psq;
    __syncthreads();
    if (t == 0) enorm[n] = (red[0] + red[1]) + (red[2] + red[3]);
}

// ---------------------------------------------------------------------------
// Kernel M: memory_bank fp32 -> fp8 e4m3 + ||m_quantized||^2.
// One wave per row (4 rows/block): no LDS, no __syncthreads.
// ---------------------------------------------------------------------------
__global__ __launch_bounds__(256) void mprep_kernel(
    const float* __restrict__ mb, uint8_t* __restrict__ mq,
    float* __restrict__ mnorm)
{
    const int r = blockIdx.x*4 + (threadIdx.x >> 6);
    const int l = threadIdx.x & 63;
    float psq = 0.f;
    unsigned ow[4];
    if (r < NMEM) {
        const float4* src = (const float4*)(mb + (size_t)r*TGT) + l*4;
#pragma unroll
        for (int i = 0; i < 4; ++i) {
            float4 v = src[i];
            __hip_fp8_e4m3 q0(v.x), q1(v.y), q2(v.z), q3(v.w);
            ow[i] = (unsigned)q0.__x | ((unsigned)q1.__x << 8)
                  | ((unsigned)q2.__x << 16) | ((unsigned)q3.__x << 24);
            float d0 = (float)q0, d1 = (float)q1, d2 = (float)q2, d3 = (float)q3;
            psq += d0*d0 + d1*d1 + d2*d2 + d3*d3;
        }
    } else {
        ow[0] = ow[1] = ow[2] = ow[3] = 0u;   // fp8 zero
    }
    uint4 o4 = make_uint4(ow[0], ow[1], ow[2], ow[3]);
    *(uint4*)(mq + (size_t)r*TGT + l*16) = o4;

    for (int off = 32; off > 0; off >>= 1) psq += __shfl_down(psq, off, 64);
    if (l == 0) mnorm[r] = (r < NMEM) ? psq : 1e30f;
}

// ---------------------------------------------------------------------------
// Kernel B: fused fp8 GEMM + min.  MX-scaled MFMA 16x16x128 (K=128/instr,
// unit scales) -> 2x bf16 rate, 1/4 staging bytes, 8 K-iters (vs 32).
// 128x128 tile, XOR-swizzled LDS: 16B chunk c of row r lives at slot
// c ^ (r&7)  -> fragment ds_read_b128 are 2-way (free) on banks.
// ---------------------------------------------------------------------------
__device__ __forceinline__ void load_lds16(const void* g, void* l)
{
    __builtin_amdgcn_global_load_lds(
        (__attribute__((address_space(1))) void*)g,
        (__attribute__((address_space(3))) void*)l, 16, 0, 0);
}

__device__ __forceinline__ intx8 read_frag(const uint8_t* base, int row, int g)
{
    const int s0 = (2*g) ^ (row & 7);           // chunk 2g   -> slot s0
    const intx4 lo = *(const intx4*)(base + row*128 + s0*16);
    const intx4 hi = *(const intx4*)(base + row*128 + (s0^1)*16); // chunk 2g+1
    intx8 r;
    r[0]=lo[0]; r[1]=lo[1]; r[2]=lo[2]; r[3]=lo[3];
    r[4]=hi[0]; r[5]=hi[1]; r[6]=hi[2]; r[7]=hi[3];
    return r;
}

__global__ __launch_bounds__(256) void nnmin_kernel(
    const uint8_t* __restrict__ E, const uint8_t* __restrict__ M,
    const float* __restrict__ enorm, const float* __restrict__ mnorm,
    int* __restrict__ out_min)
{
    __shared__ __attribute__((aligned(16))) uint8_t As[128*128];  // 16 KB
    __shared__ __attribute__((aligned(16))) uint8_t Bs[128*128];  // 16 KB

    const int m0   = blockIdx.x * 128;
    const int n0   = blockIdx.y * 128;
    const int tid  = threadIdx.x;
    const int wave = tid >> 6;
    const int lane = tid & 63;
    const int wm   = wave >> 1;
    const int wn   = wave & 1;

    // staging: wave stages 8 rows x 128 B per call; 4 calls -> 32 rows each.
    // lane -> row wave*8 + (lane>>3), LDS slot lane&7, global chunk slot^row&7.
    const int sr8 = lane >> 3;
    const int sch = ((lane & 7) ^ sr8) * 16;
    const uint8_t* gA = E + (size_t)(m0 + wave*8 + sr8)*TGT + sch;
    const uint8_t* gB = M + (size_t)(n0 + wave*8 + sr8)*TGT + sch;
    uint8_t* lA = As + wave*8*128 + lane*16;
    uint8_t* lB = Bs + wave*8*128 + lane*16;

    floatx4 acc[4][4];
#pragma unroll
    for (int i = 0; i < 4; ++i)
#pragma unroll
        for (int j = 0; j < 4; ++j) acc[i][j] = (floatx4)0.0f;

    const int fr = lane & 15;       // fragment row within 16
    const int fg = lane >> 4;       // k-group: k = fg*32 + 0..31

    for (int k0 = 0; k0 < TGT; k0 += 128) {
#pragma unroll
        for (int q = 0; q < 4; ++q) {
            load_lds16(gA + (size_t)q*32*TGT + k0, lA + q*32*128);
            load_lds16(gB + (size_t)q*32*TGT + k0, lB + q*32*128);
        }
        __syncthreads();

        intx8 a[4], b[4];
#pragma unroll
        for (int t = 0; t < 4; ++t)
            a[t] = read_frag(As, wm*64 + t*16 + fr, fg);
#pragma unroll
        for (int t = 0; t < 4; ++t)
            b[t] = read_frag(Bs, wn*64 + t*16 + fr, fg);
#pragma unroll
        for (int tm = 0; tm < 4; ++tm)
#pragma unroll
            for (int tn = 0; tn < 4; ++tn)
                acc[tm][tn] = __builtin_amdgcn_mfma_scale_f32_16x16x128_f8f6f4(
                    a[tm], b[tn], acc[tm][tn],
                    0 /*cbsz: A=fp8*/, 0 /*blgp: B=fp8*/,
                    0, 0x7f7f7f7f /*scale_a = 1.0*/,
                    0, 0x7f7f7f7f /*scale_b = 1.0*/);
        __syncthreads();
    }

    // epilogue: d2 + min over this block's 128 columns, atomicMin per row
    const int col  = lane & 15;
    const int rowq = (lane >> 4) * 4;
    const int colbase = n0 + wn*64;
#pragma unroll
    for (int tm = 0; tm < 4; ++tm) {
#pragma unroll
        for (int r = 0; r < 4; ++r) {
            int row = m0 + wm*64 + tm*16 + rowq + r;
            float en = enorm[row];
            float best = 1e38f;
#pragma unroll
            for (int tn = 0; tn < 4; ++tn) {
                float d2 = en + mnorm[colbase + tn*16 + col]
                         - 2.0f * acc[tm][tn][r];
                best = fminf(best, d2);
            }
#pragma unroll
            for (int off = 1; off < 16; off <<= 1)
                best = fminf(best, __shfl_xor(best, off, 64));
            if (col == 0)
                atomicMin(&out_min[row], __float_as_int(best));
        }
    }
}

// ---------------------------------------------------------------------------
// Kernel C1: image scores = max over 576 patches per batch
// ---------------------------------------------------------------------------
__global__ __launch_bounds__(256) void score_kernel(
    const int* __restrict__ ps_bits, float* __restrict__ out)
{
    const int b = blockIdx.x, tid = threadIdx.x;
    __shared__ float red[4];
    float m = -1e38f;
    for (int i = tid; i < GRID_*GRID_; i += 256)
        m = fmaxf(m, __int_as_float(ps_bits[b*GRID_*GRID_ + i]));
    for (int off = 32; off > 0; off >>= 1) m = fmaxf(m, __shfl_down(m, off, 64));
    if ((tid & 63) == 0) red[tid >> 6] = m;
    __syncthreads();
    if (tid == 0) out[b] = fmaxf(fmaxf(red[0], red[1]), fmaxf(red[2], red[3]));
}

// ---------------------------------------------------------------------------
// Kernel C2: bilinear 24x24 -> 384x384 (jax half-pixel == clamped bilinear)
// ---------------------------------------------------------------------------
__global__ __launch_bounds__(256) void mask_kernel(
    const int* __restrict__ ps_bits, float* __restrict__ masks)
{
    int idx = blockIdx.x*256 + threadIdx.x;
    int b  = idx / (IMG_*IMG_);
    int p  = idx - b*(IMG_*IMG_);
    int oy = p / IMG_, ox = p - oy*IMG_;

    float fy = (oy + 0.5f) * (1.0f/16.0f) - 0.5f;
    float fx = (ox + 0.5f) * (1.0f/16.0f) - 0.5f;
    int y0 = (int)floorf(fy); float ty = fy - (float)y0;
    int x0 = (int)floorf(fx); float tx = fx - (float)x0;
    int y0c = min(max(y0, 0), GRID_-1), y1c = min(max(y0+1, 0), GRID_-1);
    int x0c = min(max(x0, 0), GRID_-1), x1c = min(max(x0+1, 0), GRID_-1);

    const int* psb = ps_bits + b*GRID_*GRID_;
    float v00 = __int_as_float(psb[y0c*GRID_ + x0c]);
    float v01 = __int_as_float(psb[y0c*GRID_ + x1c]);
    float v10 = __int_as_float(psb[y1c*GRID_ + x0c]);
    float v11 = __int_as_float(psb[y1c*GRID_ + x1c]);
    float v0 = v00 + (v01 - v00)*tx;
    float v1 = v10 + (v11 - v10)*tx;
    masks[idx] = v0 + (v1 - v0)*ty;
}

// ---------------------------------------------------------------------------
extern "C" void kernel_launch(void* const* d_in, const int* in_sizes, int n_in,
                              void* d_out, int out_size, void* d_ws, size_t ws_size,
                              hipStream_t stream)
{
    const float* f6  = (const float*)d_in[0];
    const float* f8  = (const float*)d_in[1];
    const float* f10 = (const float*)d_in[2];
    const float* mb  = (const float*)d_in[3];
    float* out = (float*)d_out;

    char* ws = (char*)d_ws;
    uint8_t* emb = (uint8_t*)ws; ws += (size_t)NPATCH*TGT;       // 4.7 MB
    uint8_t* mq  = (uint8_t*)ws; ws += (size_t)NMEM_PAD*TGT;     // 20.6 MB
    float* enorm = (float*)ws;   ws += (size_t)NPATCH*sizeof(float);
    float* mnorm = (float*)ws;   ws += (size_t)NMEM_PAD*sizeof(float);
    int* psbits  = (int*)ws;     ws += (size_t)NPATCH*sizeof(int);

    hipLaunchKernelGGL(emb_kernel, dim3(NPATCH), dim3(256), 0, stream,
                       f6, f8, f10, emb, enorm, psbits);
    hipLaunchKernelGGL(mprep_kernel, dim3(NMEM_PAD/4), dim3(256), 0, stream,
                       mb, mq, mnorm);
    hipLaunchKernelGGL(nnmin_kernel, dim3(NPATCH/128, NMEM_PAD/128), dim3(256),
                       0, stream, emb, mq, enorm, mnorm, psbits);
    hipLaunchKernelGGL(score_kernel, dim3(B_), dim3(256), 0, stream,
                       psbits, out);
    hipLaunchKernelGGL(mask_kernel, dim3((B_*IMG_*IMG_)/256), dim3(256), 0, stream,
                       psbits, out + B_);
}